// Round 14
// baseline (72.071 us; speedup 1.0000x reference)
//
#include <hip/hip_runtime.h>
#include <hip/hip_bf16.h>

// Problem dims (fixed): B=8, Q=256, K=256, D=256, H=256, DV=512
#define B_  8
#define Q_  256
#define K_  256
#define D_  256
#define H_  256
#define DV_ 512
#define QB  4            // q-rows per attn block

#define SCALE_2LOG2E 2.8853900817779268f   // 2*log2(e): exp(2x) = 2^(x*this)
#define LOG2E_F      1.4426950408889634f

// ---------------------------------------------------------------------------
// Kernel 1: projections + exponentiation (exp factorization):
//   Eq [B][Q][H]  = 2^((queries @ W_q) * 2log2e)
//   EkT[B][H][K]  = 2^((keys    @ W_k)^T * 2log2e)   (transposed)
// Flat 1D grid, b = id&7 (XCD-locality with attn kernel's decode).
// ---------------------------------------------------------------------------
__global__ __launch_bounds__(256) void proj_kernel(
    const float* __restrict__ queries, const float* __restrict__ keys,
    const float* __restrict__ Wq, const float* __restrict__ Wk,
    float* __restrict__ Eq, float* __restrict__ EkT) {
  const int id = blockIdx.x;
  const int b  = id & 7;
  const bool kpath = (id >> 3) & 1;
  const int m0 = ((id >> 4) & 3) * 64;     // q-rows (qpath) or k-cols (kpath)
  const int h0 = ((id >> 6) & 3) * 64;
  const int tid = threadIdx.x;

  __shared__ float As[64][68];             // [d][row]
  __shared__ float Bs[64][68];             // [d][col]

  const int lr = tid >> 4;
  const int lc = (tid & 15) << 2;
  const int r0 = (tid & 15) << 2;
  const int c0 = (tid >> 4) << 2;

  float acc[4][4] = {};

  for (int kk = 0; kk < D_; kk += 64) {
    if (!kpath) {
      #pragma unroll
      for (int i = 0; i < 4; i++) {
        const int row = lr + i * 16;
        float4 va = *(const float4*)&queries[((size_t)(b * Q_ + m0 + row)) * D_ + kk + lc];
        As[lc + 0][row] = va.x; As[lc + 1][row] = va.y;
        As[lc + 2][row] = va.z; As[lc + 3][row] = va.w;
        float4 vb = *(const float4*)&Wq[((size_t)(kk + row)) * H_ + h0 + lc];
        *(float4*)&Bs[row][lc] = vb;
      }
    } else {
      #pragma unroll
      for (int i = 0; i < 4; i++) {
        const int row = lr + i * 16;
        float4 va = *(const float4*)&Wk[((size_t)(kk + row)) * H_ + h0 + lc];
        *(float4*)&As[row][lc] = va;
        float4 vb = *(const float4*)&keys[((size_t)(b * K_ + m0 + row)) * D_ + kk + lc];
        Bs[lc + 0][row] = vb.x; Bs[lc + 1][row] = vb.y;
        Bs[lc + 2][row] = vb.z; Bs[lc + 3][row] = vb.w;
      }
    }
    __syncthreads();

    #pragma unroll 8
    for (int d = 0; d < 64; d++) {
      float4 av = *(const float4*)&As[d][r0];
      float4 bv = *(const float4*)&Bs[d][c0];
      acc[0][0] = fmaf(av.x, bv.x, acc[0][0]); acc[0][1] = fmaf(av.x, bv.y, acc[0][1]);
      acc[0][2] = fmaf(av.x, bv.z, acc[0][2]); acc[0][3] = fmaf(av.x, bv.w, acc[0][3]);
      acc[1][0] = fmaf(av.y, bv.x, acc[1][0]); acc[1][1] = fmaf(av.y, bv.y, acc[1][1]);
      acc[1][2] = fmaf(av.y, bv.z, acc[1][2]); acc[1][3] = fmaf(av.y, bv.w, acc[1][3]);
      acc[2][0] = fmaf(av.z, bv.x, acc[2][0]); acc[2][1] = fmaf(av.z, bv.y, acc[2][1]);
      acc[2][2] = fmaf(av.z, bv.z, acc[2][2]); acc[2][3] = fmaf(av.z, bv.w, acc[2][3]);
      acc[3][0] = fmaf(av.w, bv.x, acc[3][0]); acc[3][1] = fmaf(av.w, bv.y, acc[3][1]);
      acc[3][2] = fmaf(av.w, bv.z, acc[3][2]); acc[3][3] = fmaf(av.w, bv.w, acc[3][3]);
    }
    __syncthreads();
  }

  float* dst = kpath ? EkT : Eq;
  const int ro = kpath ? h0 : m0, co = kpath ? m0 : h0;
  #pragma unroll
  for (int i = 0; i < 4; i++) {
    float4 v;
    v.x = __builtin_amdgcn_exp2f(acc[i][0] * SCALE_2LOG2E);
    v.y = __builtin_amdgcn_exp2f(acc[i][1] * SCALE_2LOG2E);
    v.z = __builtin_amdgcn_exp2f(acc[i][2] * SCALE_2LOG2E);
    v.w = __builtin_amdgcn_exp2f(acc[i][3] * SCALE_2LOG2E);
    *(float4*)&dst[((size_t)(b * 256 + ro + r0 + i)) * 256 + co + c0] = v;
  }
}

// ---------------------------------------------------------------------------
// Kernel 2: fused scores + softmax + PV — r12 body + explicit 1-deep software
// pipeline of ALL operands (global ek/v AND LDS eq/wv/attn) in both hot loops.
// Theory: every prior variant left ~120cyc LDS-broadcast + ~300cyc global
// latency exposed IN the dependency chain (VALUBusy ~30% across r7-r13,
// 3x over the VALU model). Prefetch next iteration's operands before this
// iteration's compute; st/group loops kept rolled (#pragma unroll 1) so the
// compiler can't hoist all loads and spill (r10 lesson).
// ---------------------------------------------------------------------------
__global__ __launch_bounds__(1024) void attn_kernel(
    const float* __restrict__ Eq, const float* __restrict__ EkT,
    const float* __restrict__ wv, const float* __restrict__ values,
    float* __restrict__ out) {
  const int t    = threadIdx.x;
  const int wid  = t >> 6;
  const int lane = t & 63;
  const int b    = blockIdx.x & 7;          // XCD-locality decode
  const int q0   = (blockIdx.x >> 3) * QB;

  __shared__ float rbuf[8 * 1024];         // 32 KB: score/PV partial slots
  __shared__ float eq_t[QB][H_];           // 4 KB
  __shared__ float wvm2[H_];               // 1 KB (-2*wv)
  __shared__ float attn_q[QB][K_];         // 4 KB  [qq][k]
  __shared__ float psumS[QB];

  // ---- stage eq (4 rows) + wv ----
  if (t < H_) {
    const float* qs = Eq + ((size_t)(b * Q_ + q0)) * H_ + t;
    eq_t[0][t] = qs[0];
    eq_t[1][t] = qs[H_];
    eq_t[2][t] = qs[2 * H_];
    eq_t[3][t] = qs[3 * H_];
    wvm2[t] = -2.0f * wv[t];
  }
  __syncthreads();

  // ---- score: wave's 16-h chunk, 4-way h-combined sigmoids, pipelined ----
  float4 s2v[QB];
  #pragma unroll
  for (int qq = 0; qq < QB; qq++) s2v[qq] = make_float4(0.f, 0.f, 0.f, 0.f);

  const int hbase = wid * 16;
  const float* ekb = EkT + (size_t)b * H_ * K_ + (size_t)hbase * K_ + 4 * lane;

  float4 ekc[4], eqc[QB], wvc;
  #pragma unroll
  for (int j = 0; j < 4; j++) ekc[j] = *(const float4*)(ekb + (size_t)j * K_);
  wvc = *(const float4*)&wvm2[hbase];
  #pragma unroll
  for (int qq = 0; qq < QB; qq++) eqc[qq] = *(const float4*)&eq_t[qq][hbase];

  #pragma unroll 1
  for (int st = 0; st < 4; st++) {         // 4 h per step, rolled
    float4 ekn[4], eqn[QB], wvn;
    if (st < 3) {                          // issue next step's operands NOW
      #pragma unroll
      for (int j = 0; j < 4; j++)
        ekn[j] = *(const float4*)(ekb + (size_t)((st + 1) * 4 + j) * K_);
      wvn = *(const float4*)&wvm2[hbase + (st + 1) * 4];
      #pragma unroll
      for (int qq = 0; qq < QB; qq++)
        eqn[qq] = *(const float4*)&eq_t[qq][hbase + (st + 1) * 4];
    }
    #pragma unroll
    for (int qq = 0; qq < QB; qq++) {
      float4 eqv = eqc[qq];
      float4 s2q = s2v[qq];
      #define SCORE_K(C)                                                      \
      {                                                                       \
        float d0 = fmaf(eqv.x, ekc[0].C, 1.0f);                               \
        float d1 = fmaf(eqv.y, ekc[1].C, 1.0f);                               \
        float d2 = fmaf(eqv.z, ekc[2].C, 1.0f);                               \
        float d3 = fmaf(eqv.w, ekc[3].C, 1.0f);                               \
        float p01 = d0 * d1, p23 = d2 * d3;                                   \
        float n01 = fmaf(wvc.x, d1, wvc.y * d0);                              \
        float n23 = fmaf(wvc.z, d3, wvc.w * d2);                              \
        float num = fmaf(n01, p23, n23 * p01);                                \
        s2q.C = fmaf(num, __builtin_amdgcn_rcpf(p01 * p23), s2q.C);           \
      }
      SCORE_K(x) SCORE_K(y) SCORE_K(z) SCORE_K(w)
      #undef SCORE_K
      s2v[qq] = s2q;
    }
    if (st < 3) {
      #pragma unroll
      for (int j = 0; j < 4; j++) ekc[j] = ekn[j];
      #pragma unroll
      for (int qq = 0; qq < QB; qq++) eqc[qq] = eqn[qq];
      wvc = wvn;
    }
  }

  // ---- score partial combine, two-pass into 8 slots ----
  if (wid >= 8) {
    #pragma unroll
    for (int qq = 0; qq < QB; qq++)
      *(float4*)&rbuf[(wid - 8) * 1024 + qq * 256 + 4 * lane] = s2v[qq];
  }
  __syncthreads();
  if (wid < 8) {
    #pragma unroll
    for (int qq = 0; qq < QB; qq++) {
      float* p = &rbuf[wid * 1024 + qq * 256 + 4 * lane];
      float4 o = *(const float4*)p;
      o.x += s2v[qq].x; o.y += s2v[qq].y; o.z += s2v[qq].z; o.w += s2v[qq].w;
      *(float4*)p = o;
    }
  }
  __syncthreads();

  // ---- combine + softmax: wave qg (< QB) owns row qg; lane holds 4 k ----
  if (wid < QB) {
    const int qg = wid;
    float4 sc = make_float4(0.f, 0.f, 0.f, 0.f);
    #pragma unroll
    for (int s = 0; s < 8; s++) {
      float4 p = *(const float4*)&rbuf[s * 1024 + qg * 256 + 4 * lane];
      sc.x += p.x; sc.y += p.y; sc.z += p.z; sc.w += p.w;
    }
    float m = fmaxf(fmaxf(sc.x, sc.y), fmaxf(sc.z, sc.w));
    #pragma unroll
    for (int mask = 32; mask >= 1; mask >>= 1) m = fmaxf(m, __shfl_xor(m, mask));
    float4 e;
    e.x = __builtin_amdgcn_exp2f((sc.x - m) * LOG2E_F);
    e.y = __builtin_amdgcn_exp2f((sc.y - m) * LOG2E_F);
    e.z = __builtin_amdgcn_exp2f((sc.z - m) * LOG2E_F);
    e.w = __builtin_amdgcn_exp2f((sc.w - m) * LOG2E_F);
    float sl = (e.x + e.y) + (e.z + e.w);
    #pragma unroll
    for (int mask = 32; mask >= 1; mask >>= 1) sl += __shfl_xor(sl, mask);
    if (lane == 0) psumS[qg] = sl;
    *(float4*)&attn_q[qg][4 * lane] = e;   // contiguous b128, conflict-free
  }
  __syncthreads();

  // ---- PV: wave = (kr owns 32 k) x (dvh half); lane owns 4 dv; pipelined ----
  const int kr  = wid >> 1;
  const int dvh = wid & 1;
  const int kbase = kr * 32;
  const float* vbase = values + (size_t)b * K_ * DV_ + dvh * 256 + 4 * lane;
  float4 pacc[QB];
  #pragma unroll
  for (int qq = 0; qq < QB; qq++) pacc[qq] = make_float4(0.f, 0.f, 0.f, 0.f);

  float4 vc[4], ac[QB];
  #pragma unroll
  for (int i = 0; i < 4; i++)
    vc[i] = *(const float4*)(vbase + (size_t)(kbase + i) * DV_);
  #pragma unroll
  for (int qq = 0; qq < QB; qq++)
    ac[qq] = *(const float4*)&attn_q[qq][kbase];      // 4 k per b128

  #pragma unroll 1
  for (int g = 0; g < 8; g++) {            // groups of 4 k, rolled
    float4 vn[4], an[QB];
    if (g < 7) {                           // issue next group's operands NOW
      #pragma unroll
      for (int i = 0; i < 4; i++)
        vn[i] = *(const float4*)(vbase + (size_t)(kbase + (g + 1) * 4 + i) * DV_);
      #pragma unroll
      for (int qq = 0; qq < QB; qq++)
        an[qq] = *(const float4*)&attn_q[qq][kbase + (g + 1) * 4];
    }
    #define PV_STEP(i, C)                                                     \
    {                                                                         \
      float4 v = vc[i];                                                       \
      pacc[0].x = fmaf(ac[0].C, v.x, pacc[0].x);                              \
      pacc[0].y = fmaf(ac[0].C, v.y, pacc[0].y);                              \
      pacc[0].z = fmaf(ac[0].C, v.z, pacc[0].z);                              \
      pacc[0].w = fmaf(ac[0].C, v.w, pacc[0].w);                              \
      pacc[1].x = fmaf(ac[1].C, v.x, pacc[1].x);                              \
      pacc[1].y = fmaf(ac[1].C, v.y, pacc[1].y);                              \
      pacc[1].z = fmaf(ac[1].C, v.z, pacc[1].z);                              \
      pacc[1].w = fmaf(ac[1].C, v.w, pacc[1].w);                              \
      pacc[2].x = fmaf(ac[2].C, v.x, pacc[2].x);                              \
      pacc[2].y = fmaf(ac[2].C, v.y, pacc[2].y);                              \
      pacc[2].z = fmaf(ac[2].C, v.z, pacc[2].z);                              \
      pacc[2].w = fmaf(ac[2].C, v.w, pacc[2].w);                              \
      pacc[3].x = fmaf(ac[3].C, v.x, pacc[3].x);                              \
      pacc[3].y = fmaf(ac[3].C, v.y, pacc[3].y);                              \
      pacc[3].z = fmaf(ac[3].C, v.z, pacc[3].z);                              \
      pacc[3].w = fmaf(ac[3].C, v.w, pacc[3].w);                              \
    }
    PV_STEP(0, x) PV_STEP(1, y) PV_STEP(2, z) PV_STEP(3, w)
    #undef PV_STEP
    if (g < 7) {
      #pragma unroll
      for (int i = 0; i < 4; i++) vc[i] = vn[i];
      #pragma unroll
      for (int qq = 0; qq < QB; qq++) ac[qq] = an[qq];
    }
  }

  // ---- PV partial combine, two-pass into 8 slots (wid & wid+8 same dvh) ----
  if (wid >= 8) {
    #pragma unroll
    for (int qq = 0; qq < QB; qq++)
      *(float4*)&rbuf[(wid - 8) * 1024 + qq * 256 + 4 * lane] = pacc[qq];
  }
  __syncthreads();
  if (wid < 8) {
    #pragma unroll
    for (int qq = 0; qq < QB; qq++) {
      float* p = &rbuf[wid * 1024 + qq * 256 + 4 * lane];
      float4 o = *(const float4*)p;
      o.x += pacc[qq].x; o.y += pacc[qq].y; o.z += pacc[qq].z; o.w += pacc[qq].w;
      *(float4*)p = o;
    }
  }
  __syncthreads();

  // ---- final combine + output by waves 0 (dvh=0) and 1 (dvh=1): 4 slots ----
  if (wid < 2) {
    float4 oacc[QB];
    #pragma unroll
    for (int qq = 0; qq < QB; qq++) oacc[qq] = make_float4(0.f, 0.f, 0.f, 0.f);
    #pragma unroll
    for (int p = 0; p < 4; p++) {
      const float* r = &rbuf[(2 * p + wid) * 1024];
      #pragma unroll
      for (int qq = 0; qq < QB; qq++) {
        float4 pp = *(const float4*)&r[qq * 256 + 4 * lane];
        oacc[qq].x += pp.x; oacc[qq].y += pp.y;
        oacc[qq].z += pp.z; oacc[qq].w += pp.w;
      }
    }
    #pragma unroll
    for (int qq = 0; qq < QB; qq++) {
      float rs = __builtin_amdgcn_rcpf(psumS[qq]);
      float4 o = make_float4(oacc[qq].x * rs, oacc[qq].y * rs,
                             oacc[qq].z * rs, oacc[qq].w * rs);
      *(float4*)&out[((size_t)(b * Q_ + q0 + qq)) * DV_ + wid * 256 + 4 * lane] = o;
    }
  }
}

extern "C" void kernel_launch(void* const* d_in, const int* in_sizes, int n_in,
                              void* d_out, int out_size, void* d_ws, size_t ws_size,
                              hipStream_t stream) {
  const float* queries = (const float*)d_in[0];  // [8,256,256]
  const float* keys    = (const float*)d_in[1];  // [8,256,256]
  const float* values  = (const float*)d_in[2];  // [8,256,512]
  const float* W_q     = (const float*)d_in[3];  // [256,256]
  const float* W_k     = (const float*)d_in[4];  // [256,256]
  const float* w_v     = (const float*)d_in[5];  // [256]
  float* out = (float*)d_out;

  float* Eq  = (float*)d_ws;                     // [8][256][256] = 2 MB
  float* EkT = Eq + (size_t)B_ * Q_ * H_;        // [8][256][256] = 2 MB

  dim3 pgrid(256), pblk(256);
  proj_kernel<<<pgrid, pblk, 0, stream>>>(queries, keys, W_q, W_k, Eq, EkT);

  dim3 agrid(Q_ / QB * B_), ablk(1024);
  attn_kernel<<<agrid, ablk, 0, stream>>>(Eq, EkT, w_v, values, out);
}

// Round 15
// 46.610 us; speedup vs baseline: 1.5462x; 1.5462x over previous
//
#include <hip/hip_runtime.h>
#include <hip/hip_bf16.h>

// Problem dims (fixed): B=8, Q=256, K=256, D=256, H=256, DV=512
#define B_  8
#define Q_  256
#define K_  256
#define D_  256
#define H_  256
#define DV_ 512
#define QB  4            // q-rows per score block

#define SCALE_2LOG2E 2.8853900817779268f   // 2*log2(e): exp(2x) = 2^(x*this)
#define LOG2E_F      1.4426950408889634f

// ---------------------------------------------------------------------------
// Kernel 1: projections + exponentiation (exp factorization):
//   Eq [B][Q][H]  = 2^((queries @ W_q) * 2log2e)
//   EkT[B][H][K]  = 2^((keys    @ W_k)^T * 2log2e)   (transposed)
// Flat 1D grid, b = id&7 (XCD-locality).  Measured ~3 us.
// ---------------------------------------------------------------------------
__global__ __launch_bounds__(256) void proj_kernel(
    const float* __restrict__ queries, const float* __restrict__ keys,
    const float* __restrict__ Wq, const float* __restrict__ Wk,
    float* __restrict__ Eq, float* __restrict__ EkT) {
  const int id = blockIdx.x;
  const int b  = id & 7;
  const bool kpath = (id >> 3) & 1;
  const int m0 = ((id >> 4) & 3) * 64;     // q-rows (qpath) or k-cols (kpath)
  const int h0 = ((id >> 6) & 3) * 64;
  const int tid = threadIdx.x;

  __shared__ float As[64][68];             // [d][row]
  __shared__ float Bs[64][68];             // [d][col]

  const int lr = tid >> 4;
  const int lc = (tid & 15) << 2;
  const int r0 = (tid & 15) << 2;
  const int c0 = (tid >> 4) << 2;

  float acc[4][4] = {};

  for (int kk = 0; kk < D_; kk += 64) {
    if (!kpath) {
      #pragma unroll
      for (int i = 0; i < 4; i++) {
        const int row = lr + i * 16;
        float4 va = *(const float4*)&queries[((size_t)(b * Q_ + m0 + row)) * D_ + kk + lc];
        As[lc + 0][row] = va.x; As[lc + 1][row] = va.y;
        As[lc + 2][row] = va.z; As[lc + 3][row] = va.w;
        float4 vb = *(const float4*)&Wq[((size_t)(kk + row)) * H_ + h0 + lc];
        *(float4*)&Bs[row][lc] = vb;
      }
    } else {
      #pragma unroll
      for (int i = 0; i < 4; i++) {
        const int row = lr + i * 16;
        float4 va = *(const float4*)&Wk[((size_t)(kk + row)) * H_ + h0 + lc];
        *(float4*)&As[row][lc] = va;
        float4 vb = *(const float4*)&keys[((size_t)(b * K_ + m0 + row)) * D_ + kk + lc];
        Bs[lc + 0][row] = vb.x; Bs[lc + 1][row] = vb.y;
        Bs[lc + 2][row] = vb.z; Bs[lc + 3][row] = vb.w;
      }
    }
    __syncthreads();

    #pragma unroll 8
    for (int d = 0; d < 64; d++) {
      float4 av = *(const float4*)&As[d][r0];
      float4 bv = *(const float4*)&Bs[d][c0];
      acc[0][0] = fmaf(av.x, bv.x, acc[0][0]); acc[0][1] = fmaf(av.x, bv.y, acc[0][1]);
      acc[0][2] = fmaf(av.x, bv.z, acc[0][2]); acc[0][3] = fmaf(av.x, bv.w, acc[0][3]);
      acc[1][0] = fmaf(av.y, bv.x, acc[1][0]); acc[1][1] = fmaf(av.y, bv.y, acc[1][1]);
      acc[1][2] = fmaf(av.y, bv.z, acc[1][2]); acc[1][3] = fmaf(av.y, bv.w, acc[1][3]);
      acc[2][0] = fmaf(av.z, bv.x, acc[2][0]); acc[2][1] = fmaf(av.z, bv.y, acc[2][1]);
      acc[2][2] = fmaf(av.z, bv.z, acc[2][2]); acc[2][3] = fmaf(av.z, bv.w, acc[2][3]);
      acc[3][0] = fmaf(av.w, bv.x, acc[3][0]); acc[3][1] = fmaf(av.w, bv.y, acc[3][1]);
      acc[3][2] = fmaf(av.w, bv.z, acc[3][2]); acc[3][3] = fmaf(av.w, bv.w, acc[3][3]);
    }
    __syncthreads();
  }

  float* dst = kpath ? EkT : Eq;
  const int ro = kpath ? h0 : m0, co = kpath ? m0 : h0;
  #pragma unroll
  for (int i = 0; i < 4; i++) {
    float4 v;
    v.x = __builtin_amdgcn_exp2f(acc[i][0] * SCALE_2LOG2E);
    v.y = __builtin_amdgcn_exp2f(acc[i][1] * SCALE_2LOG2E);
    v.z = __builtin_amdgcn_exp2f(acc[i][2] * SCALE_2LOG2E);
    v.w = __builtin_amdgcn_exp2f(acc[i][3] * SCALE_2LOG2E);
    *(float4*)&dst[((size_t)(b * 256 + ro + r0 + i)) * 256 + co + c0] = v;
  }
}

// ---------------------------------------------------------------------------
// Kernel 2: scores + softmax ONLY.  512-thread blocks (8 waves), QB=4,
// grid 512 -> 2 blocks/CU co-resident (16 waves/CU is the VGPR=64 cap; with
// 1024-thr blocks that was ONE block in lockstep — every load stall hit all
// waves at once).  Two blocks at independent phases fill each other's stalls.
// SCORE: wave wid owns h-chunk [32*wid,+32) (8 st steps -> longer per-wave
//        load pipeline), lane owns k=4*lane..+3, 4 q in s2v[4] (float4 over k).
//        4-way h-combined sigmoids (1 rcp / 4 h).
// REDUCE: two-pass into 4 slots; wave qg<4 sums 4 slots for row qg, softmax
//        in-wave, writes NORMALIZED attn row to ws (PV needs no psum).
// ---------------------------------------------------------------------------
__global__ __launch_bounds__(512) void score_kernel(
    const float* __restrict__ Eq, const float* __restrict__ EkT,
    const float* __restrict__ wv, float* __restrict__ attn) {
  const int t    = threadIdx.x;
  const int wid  = t >> 6;                 // 0..7
  const int lane = t & 63;
  const int b    = blockIdx.x & 7;         // XCD-locality decode
  const int q0   = (blockIdx.x >> 3) * QB;

  __shared__ float rbuf[4 * 1024];         // 16 KB: two-pass partial slots
  __shared__ float eq_t[QB][H_];           // 4 KB
  __shared__ float wvm2[H_];               // 1 KB (-2*wv)

  // ---- stage eq (4 rows) + wv ----
  if (t < H_) {
    const float* qs = Eq + ((size_t)(b * Q_ + q0)) * H_ + t;
    eq_t[0][t] = qs[0];
    eq_t[1][t] = qs[H_];
    eq_t[2][t] = qs[2 * H_];
    eq_t[3][t] = qs[3 * H_];
    wvm2[t] = -2.0f * wv[t];
  }
  __syncthreads();

  // ---- score: wave's 32-h chunk, 4-way h-combined sigmoids ----
  float4 s2v[QB];
  #pragma unroll
  for (int qq = 0; qq < QB; qq++) s2v[qq] = make_float4(0.f, 0.f, 0.f, 0.f);

  const int hbase = wid * 32;
  const float* ekb = EkT + (size_t)b * H_ * K_ + (size_t)hbase * K_ + 4 * lane;

  for (int st = 0; st < 8; st++) {         // 4 h per step
    float4 ekc[4];
    #pragma unroll
    for (int j = 0; j < 4; j++)
      ekc[j] = *(const float4*)(ekb + (size_t)(st * 4 + j) * K_);
    const int h = hbase + st * 4;
    float4 wvv = *(const float4*)&wvm2[h];
    #pragma unroll
    for (int qq = 0; qq < QB; qq++) {
      float4 eqv = *(const float4*)&eq_t[qq][h];
      float4 s2q = s2v[qq];
      #define SCORE_K(C)                                                      \
      {                                                                       \
        float d0 = fmaf(eqv.x, ekc[0].C, 1.0f);                               \
        float d1 = fmaf(eqv.y, ekc[1].C, 1.0f);                               \
        float d2 = fmaf(eqv.z, ekc[2].C, 1.0f);                               \
        float d3 = fmaf(eqv.w, ekc[3].C, 1.0f);                               \
        float p01 = d0 * d1, p23 = d2 * d3;                                   \
        float n01 = fmaf(wvv.x, d1, wvv.y * d0);                              \
        float n23 = fmaf(wvv.z, d3, wvv.w * d2);                              \
        float num = fmaf(n01, p23, n23 * p01);                                \
        s2q.C = fmaf(num, __builtin_amdgcn_rcpf(p01 * p23), s2q.C);           \
      }
      SCORE_K(x) SCORE_K(y) SCORE_K(z) SCORE_K(w)
      #undef SCORE_K
      s2v[qq] = s2q;
    }
  }

  // ---- two-pass combine into 4 slots (contiguous runs, conflict-free) ----
  if (wid >= 4) {
    #pragma unroll
    for (int qq = 0; qq < QB; qq++)
      *(float4*)&rbuf[(wid - 4) * 1024 + qq * 256 + 4 * lane] = s2v[qq];
  }
  __syncthreads();
  if (wid < 4) {
    #pragma unroll
    for (int qq = 0; qq < QB; qq++) {
      float* p = &rbuf[wid * 1024 + qq * 256 + 4 * lane];
      float4 o = *(const float4*)p;
      o.x += s2v[qq].x; o.y += s2v[qq].y; o.z += s2v[qq].z; o.w += s2v[qq].w;
      *(float4*)p = o;
    }
  }
  __syncthreads();

  // ---- softmax + normalized store: wave qg owns row qg; lane holds 4 k ----
  if (wid < QB) {
    const int qg = wid;
    float4 sc = make_float4(0.f, 0.f, 0.f, 0.f);
    #pragma unroll
    for (int s = 0; s < 4; s++) {
      float4 p = *(const float4*)&rbuf[s * 1024 + qg * 256 + 4 * lane];
      sc.x += p.x; sc.y += p.y; sc.z += p.z; sc.w += p.w;
    }
    float m = fmaxf(fmaxf(sc.x, sc.y), fmaxf(sc.z, sc.w));
    #pragma unroll
    for (int mask = 32; mask >= 1; mask >>= 1) m = fmaxf(m, __shfl_xor(m, mask));
    float4 e;
    e.x = __builtin_amdgcn_exp2f((sc.x - m) * LOG2E_F);
    e.y = __builtin_amdgcn_exp2f((sc.y - m) * LOG2E_F);
    e.z = __builtin_amdgcn_exp2f((sc.z - m) * LOG2E_F);
    e.w = __builtin_amdgcn_exp2f((sc.w - m) * LOG2E_F);
    float sl = (e.x + e.y) + (e.z + e.w);
    #pragma unroll
    for (int mask = 32; mask >= 1; mask >>= 1) sl += __shfl_xor(sl, mask);
    float rs = __builtin_amdgcn_rcpf(sl);
    float4 o = make_float4(e.x * rs, e.y * rs, e.z * rs, e.w * rs);
    *(float4*)&attn[((size_t)(b * Q_ + q0 + qg)) * K_ + 4 * lane] = o;
  }
}

// ---------------------------------------------------------------------------
// Kernel 3: PV GEMM  out[b] = attn[b](256x256) @ values[b](256x512).
// proj-clone: 64x64 tiles, grid 256 (b=id&7, qt=(id>>3)&3, dvt=id>>5).
// attn rows are pre-normalized: no epilogue scaling.  ~3-5 us.
// ---------------------------------------------------------------------------
__global__ __launch_bounds__(256) void pv_kernel(
    const float* __restrict__ attn, const float* __restrict__ values,
    float* __restrict__ out) {
  const int id  = blockIdx.x;
  const int b   = id & 7;
  const int qt  = (id >> 3) & 3;           // 64-q tile
  const int dvt = id >> 5;                 // 64-dv tile (0..7)
  const int tid = threadIdx.x;

  __shared__ float As[64][68];             // [k][q]  (attn^T tile)
  __shared__ float Bs[64][68];             // [k][dv] (values tile)

  const int lr = tid >> 4;
  const int lc = (tid & 15) << 2;
  const int r0 = (tid & 15) << 2;
  const int c0 = (tid >> 4) << 2;

  float acc[4][4] = {};

  for (int kk = 0; kk < K_; kk += 64) {
    #pragma unroll
    for (int i = 0; i < 4; i++) {
      const int row = lr + i * 16;
      float4 va = *(const float4*)&attn[((size_t)(b * Q_ + qt * 64 + row)) * K_ + kk + lc];
      As[lc + 0][row] = va.x; As[lc + 1][row] = va.y;
      As[lc + 2][row] = va.z; As[lc + 3][row] = va.w;
      float4 vb = *(const float4*)&values[((size_t)(b * K_ + kk + row)) * DV_ + dvt * 64 + lc];
      *(float4*)&Bs[row][lc] = vb;
    }
    __syncthreads();

    #pragma unroll 8
    for (int d = 0; d < 64; d++) {
      float4 av = *(const float4*)&As[d][r0];
      float4 bv = *(const float4*)&Bs[d][c0];
      acc[0][0] = fmaf(av.x, bv.x, acc[0][0]); acc[0][1] = fmaf(av.x, bv.y, acc[0][1]);
      acc[0][2] = fmaf(av.x, bv.z, acc[0][2]); acc[0][3] = fmaf(av.x, bv.w, acc[0][3]);
      acc[1][0] = fmaf(av.y, bv.x, acc[1][0]); acc[1][1] = fmaf(av.y, bv.y, acc[1][1]);
      acc[1][2] = fmaf(av.y, bv.z, acc[1][2]); acc[1][3] = fmaf(av.y, bv.w, acc[1][3]);
      acc[2][0] = fmaf(av.z, bv.x, acc[2][0]); acc[2][1] = fmaf(av.z, bv.y, acc[2][1]);
      acc[2][2] = fmaf(av.z, bv.z, acc[2][2]); acc[2][3] = fmaf(av.z, bv.w, acc[2][3]);
      acc[3][0] = fmaf(av.w, bv.x, acc[3][0]); acc[3][1] = fmaf(av.w, bv.y, acc[3][1]);
      acc[3][2] = fmaf(av.w, bv.z, acc[3][2]); acc[3][3] = fmaf(av.w, bv.w, acc[3][3]);
    }
    __syncthreads();
  }

  #pragma unroll
  for (int i = 0; i < 4; i++) {
    float4 o = make_float4(acc[i][0], acc[i][1], acc[i][2], acc[i][3]);
    *(float4*)&out[((size_t)(b * Q_ + qt * 64 + r0 + i)) * DV_ + dvt * 64 + c0] = o;
  }
}

extern "C" void kernel_launch(void* const* d_in, const int* in_sizes, int n_in,
                              void* d_out, int out_size, void* d_ws, size_t ws_size,
                              hipStream_t stream) {
  const float* queries = (const float*)d_in[0];  // [8,256,256]
  const float* keys    = (const float*)d_in[1];  // [8,256,256]
  const float* values  = (const float*)d_in[2];  // [8,256,512]
  const float* W_q     = (const float*)d_in[3];  // [256,256]
  const float* W_k     = (const float*)d_in[4];  // [256,256]
  const float* w_v     = (const float*)d_in[5];  // [256]
  float* out = (float*)d_out;

  float* Eq   = (float*)d_ws;                    // [8][256][256] = 2 MB
  float* EkT  = Eq  + (size_t)B_ * Q_ * H_;      // [8][256][256] = 2 MB
  float* attn = EkT + (size_t)B_ * H_ * K_;      // [8][256][256] = 2 MB

  dim3 pgrid(256), pblk(256);
  proj_kernel<<<pgrid, pblk, 0, stream>>>(queries, keys, W_q, W_k, Eq, EkT);

  dim3 sgrid(Q_ / QB * B_), sblk(512);           // 512 blocks, 2/CU
  score_kernel<<<sgrid, sblk, 0, stream>>>(Eq, EkT, w_v, attn);

  dim3 vgrid(256), vblk(256);
  pv_kernel<<<vgrid, vblk, 0, stream>>>(attn, values, out);
}

// Round 16
// 43.487 us; speedup vs baseline: 1.6573x; 1.0718x over previous
//
#include <hip/hip_runtime.h>
#include <hip/hip_bf16.h>

// Problem dims (fixed): B=8, Q=256, K=256, D=256, H=256, DV=512
#define B_  8
#define Q_  256
#define K_  256
#define D_  256
#define H_  256
#define DV_ 512
#define QB  4            // q-rows per score block

#define SCALE_2LOG2E 2.8853900817779268f   // 2*log2(e): exp(2x) = 2^(x*this)
#define LOG2E_F      1.4426950408889634f

// ---------------------------------------------------------------------------
// Kernel 1: projections + exponentiation (exp factorization):
//   Eq [B][Q][H]  = 2^((queries @ W_q) * 2log2e)
//   EkT[B][H][K]  = 2^((keys    @ W_k)^T * 2log2e)   (transposed)
// Flat 1D grid, b = id&7 (XCD-locality).
// ---------------------------------------------------------------------------
__global__ __launch_bounds__(256) void proj_kernel(
    const float* __restrict__ queries, const float* __restrict__ keys,
    const float* __restrict__ Wq, const float* __restrict__ Wk,
    float* __restrict__ Eq, float* __restrict__ EkT) {
  const int id = blockIdx.x;
  const int b  = id & 7;
  const bool kpath = (id >> 3) & 1;
  const int m0 = ((id >> 4) & 3) * 64;     // q-rows (qpath) or k-cols (kpath)
  const int h0 = ((id >> 6) & 3) * 64;
  const int tid = threadIdx.x;

  __shared__ float As[64][68];             // [d][row]
  __shared__ float Bs[64][68];             // [d][col]

  const int lr = tid >> 4;
  const int lc = (tid & 15) << 2;
  const int r0 = (tid & 15) << 2;
  const int c0 = (tid >> 4) << 2;

  float acc[4][4] = {};

  for (int kk = 0; kk < D_; kk += 64) {
    if (!kpath) {
      #pragma unroll
      for (int i = 0; i < 4; i++) {
        const int row = lr + i * 16;
        float4 va = *(const float4*)&queries[((size_t)(b * Q_ + m0 + row)) * D_ + kk + lc];
        As[lc + 0][row] = va.x; As[lc + 1][row] = va.y;
        As[lc + 2][row] = va.z; As[lc + 3][row] = va.w;
        float4 vb = *(const float4*)&Wq[((size_t)(kk + row)) * H_ + h0 + lc];
        *(float4*)&Bs[row][lc] = vb;
      }
    } else {
      #pragma unroll
      for (int i = 0; i < 4; i++) {
        const int row = lr + i * 16;
        float4 va = *(const float4*)&Wk[((size_t)(kk + row)) * H_ + h0 + lc];
        *(float4*)&As[row][lc] = va;
        float4 vb = *(const float4*)&keys[((size_t)(b * K_ + m0 + row)) * D_ + kk + lc];
        Bs[lc + 0][row] = vb.x; Bs[lc + 1][row] = vb.y;
        Bs[lc + 2][row] = vb.z; Bs[lc + 3][row] = vb.w;
      }
    }
    __syncthreads();

    #pragma unroll 8
    for (int d = 0; d < 64; d++) {
      float4 av = *(const float4*)&As[d][r0];
      float4 bv = *(const float4*)&Bs[d][c0];
      acc[0][0] = fmaf(av.x, bv.x, acc[0][0]); acc[0][1] = fmaf(av.x, bv.y, acc[0][1]);
      acc[0][2] = fmaf(av.x, bv.z, acc[0][2]); acc[0][3] = fmaf(av.x, bv.w, acc[0][3]);
      acc[1][0] = fmaf(av.y, bv.x, acc[1][0]); acc[1][1] = fmaf(av.y, bv.y, acc[1][1]);
      acc[1][2] = fmaf(av.y, bv.z, acc[1][2]); acc[1][3] = fmaf(av.y, bv.w, acc[1][3]);
      acc[2][0] = fmaf(av.z, bv.x, acc[2][0]); acc[2][1] = fmaf(av.z, bv.y, acc[2][1]);
      acc[2][2] = fmaf(av.z, bv.z, acc[2][2]); acc[2][3] = fmaf(av.z, bv.w, acc[2][3]);
      acc[3][0] = fmaf(av.w, bv.x, acc[3][0]); acc[3][1] = fmaf(av.w, bv.y, acc[3][1]);
      acc[3][2] = fmaf(av.w, bv.z, acc[3][2]); acc[3][3] = fmaf(av.w, bv.w, acc[3][3]);
    }
    __syncthreads();
  }

  float* dst = kpath ? EkT : Eq;
  const int ro = kpath ? h0 : m0, co = kpath ? m0 : h0;
  #pragma unroll
  for (int i = 0; i < 4; i++) {
    float4 v;
    v.x = __builtin_amdgcn_exp2f(acc[i][0] * SCALE_2LOG2E);
    v.y = __builtin_amdgcn_exp2f(acc[i][1] * SCALE_2LOG2E);
    v.z = __builtin_amdgcn_exp2f(acc[i][2] * SCALE_2LOG2E);
    v.w = __builtin_amdgcn_exp2f(acc[i][3] * SCALE_2LOG2E);
    *(float4*)&dst[((size_t)(b * 256 + ro + r0 + i)) * 256 + co + c0] = v;
  }
}

// ---------------------------------------------------------------------------
// Kernel 2: scores + softmax.  512 threads (8 waves), QB=4, grid 512.
// CHANGE vs r15 (single mechanism): the wave-uniform operands Eq[qq][h] and
// wv[h] are read DIRECTLY FROM GLOBAL with wave-uniform addresses
// (readfirstlane-forced scalar provenance -> s_load through the scalar
// cache) instead of LDS broadcasts. Every prior structure kept 5 LDS
// broadcast reads (~120cyc each) in the st-step dependency chain — the one
// operand class never removed across r7-r15's persistent 3x issue-stall.
// Also deletes the eq/wv staging phase + its barrier; -2 scale folded into
// the post-loop (linear). VGPR drops to ~40-48 -> more waves/SIMD.
// ---------------------------------------------------------------------------
__global__ __launch_bounds__(512) void score_kernel(
    const float* __restrict__ Eq, const float* __restrict__ EkT,
    const float* __restrict__ wv, float* __restrict__ attn) {
  const int t    = threadIdx.x;
  const int wid  = __builtin_amdgcn_readfirstlane(t >> 6);   // wave-uniform
  const int lane = t & 63;
  const int b    = blockIdx.x & 7;         // XCD-locality decode
  const int q0   = (blockIdx.x >> 3) * QB;

  __shared__ float rbuf[4 * 1024];         // 16 KB: two-pass partial slots

  // ---- score: wave's 32-h chunk, 4-way h-combined sigmoids ----
  float4 s2v[QB];
  #pragma unroll
  for (int qq = 0; qq < QB; qq++) s2v[qq] = make_float4(0.f, 0.f, 0.f, 0.f);

  const int hbase = wid * 32;
  const float* ekb = EkT + (size_t)b * H_ * K_ + (size_t)hbase * K_ + 4 * lane;
  const float* eq0 = Eq + ((size_t)(b * Q_ + q0)) * H_ + hbase;  // +qq*H_ rows
  const float* wv0 = wv + hbase;

  for (int st = 0; st < 8; st++) {         // 4 h per step
    float4 ekc[4];
    #pragma unroll
    for (int j = 0; j < 4; j++)
      ekc[j] = *(const float4*)(ekb + (size_t)(st * 4 + j) * K_);
    const int h = st * 4;
    float4 wvv = *(const float4*)&wv0[h];                  // uniform -> s_load
    float4 eqv0 = *(const float4*)&eq0[0 * H_ + h];        // uniform -> s_load
    float4 eqv1 = *(const float4*)&eq0[1 * H_ + h];
    float4 eqv2 = *(const float4*)&eq0[2 * H_ + h];
    float4 eqv3 = *(const float4*)&eq0[3 * H_ + h];
    #define SCORE_Q(qq, eqv)                                                  \
    {                                                                         \
      float4 s2q = s2v[qq];                                                   \
      /* per k-component: 4 h combined per rcp */                             \
      _Pragma("unroll")                                                       \
      for (int c = 0; c < 1; c++) { /* scope */ }                             \
      {                                                                       \
        float d0, d1, d2, d3, p01, p23, n01, n23, num;                        \
        d0 = fmaf(eqv.x, ekc[0].x, 1.0f); d1 = fmaf(eqv.y, ekc[1].x, 1.0f);   \
        d2 = fmaf(eqv.z, ekc[2].x, 1.0f); d3 = fmaf(eqv.w, ekc[3].x, 1.0f);   \
        p01 = d0 * d1; p23 = d2 * d3;                                         \
        n01 = fmaf(wvv.x, d1, wvv.y * d0); n23 = fmaf(wvv.z, d3, wvv.w * d2); \
        num = fmaf(n01, p23, n23 * p01);                                      \
        s2q.x = fmaf(num, __builtin_amdgcn_rcpf(p01 * p23), s2q.x);           \
        d0 = fmaf(eqv.x, ekc[0].y, 1.0f); d1 = fmaf(eqv.y, ekc[1].y, 1.0f);   \
        d2 = fmaf(eqv.z, ekc[2].y, 1.0f); d3 = fmaf(eqv.w, ekc[3].y, 1.0f);   \
        p01 = d0 * d1; p23 = d2 * d3;                                         \
        n01 = fmaf(wvv.x, d1, wvv.y * d0); n23 = fmaf(wvv.z, d3, wvv.w * d2); \
        num = fmaf(n01, p23, n23 * p01);                                      \
        s2q.y = fmaf(num, __builtin_amdgcn_rcpf(p01 * p23), s2q.y);           \
        d0 = fmaf(eqv.x, ekc[0].z, 1.0f); d1 = fmaf(eqv.y, ekc[1].z, 1.0f);   \
        d2 = fmaf(eqv.z, ekc[2].z, 1.0f); d3 = fmaf(eqv.w, ekc[3].z, 1.0f);   \
        p01 = d0 * d1; p23 = d2 * d3;                                         \
        n01 = fmaf(wvv.x, d1, wvv.y * d0); n23 = fmaf(wvv.z, d3, wvv.w * d2); \
        num = fmaf(n01, p23, n23 * p01);                                      \
        s2q.z = fmaf(num, __builtin_amdgcn_rcpf(p01 * p23), s2q.z);           \
        d0 = fmaf(eqv.x, ekc[0].w, 1.0f); d1 = fmaf(eqv.y, ekc[1].w, 1.0f);   \
        d2 = fmaf(eqv.z, ekc[2].w, 1.0f); d3 = fmaf(eqv.w, ekc[3].w, 1.0f);   \
        p01 = d0 * d1; p23 = d2 * d3;                                         \
        n01 = fmaf(wvv.x, d1, wvv.y * d0); n23 = fmaf(wvv.z, d3, wvv.w * d2); \
        num = fmaf(n01, p23, n23 * p01);                                      \
        s2q.w = fmaf(num, __builtin_amdgcn_rcpf(p01 * p23), s2q.w);           \
      }                                                                       \
      s2v[qq] = s2q;                                                          \
    }
    SCORE_Q(0, eqv0) SCORE_Q(1, eqv1) SCORE_Q(2, eqv2) SCORE_Q(3, eqv3)
    #undef SCORE_Q
  }

  // ---- two-pass combine into 4 slots (contiguous runs, conflict-free) ----
  if (wid >= 4) {
    #pragma unroll
    for (int qq = 0; qq < QB; qq++)
      *(float4*)&rbuf[(wid - 4) * 1024 + qq * 256 + 4 * lane] = s2v[qq];
  }
  __syncthreads();
  if (wid < 4) {
    #pragma unroll
    for (int qq = 0; qq < QB; qq++) {
      float* p = &rbuf[wid * 1024 + qq * 256 + 4 * lane];
      float4 o = *(const float4*)p;
      o.x += s2v[qq].x; o.y += s2v[qq].y; o.z += s2v[qq].z; o.w += s2v[qq].w;
      *(float4*)p = o;
    }
  }
  __syncthreads();

  // ---- softmax + normalized store: wave qg owns row qg; lane holds 4 k ----
  if (wid < QB) {
    const int qg = wid;
    float4 sc = make_float4(0.f, 0.f, 0.f, 0.f);
    #pragma unroll
    for (int s = 0; s < 4; s++) {
      float4 p = *(const float4*)&rbuf[s * 1024 + qg * 256 + 4 * lane];
      sc.x += p.x; sc.y += p.y; sc.z += p.z; sc.w += p.w;
    }
    // fold the -2 factor here (linear in the partial sums)
    sc.x *= -2.0f; sc.y *= -2.0f; sc.z *= -2.0f; sc.w *= -2.0f;
    float m = fmaxf(fmaxf(sc.x, sc.y), fmaxf(sc.z, sc.w));
    #pragma unroll
    for (int mask = 32; mask >= 1; mask >>= 1) m = fmaxf(m, __shfl_xor(m, mask));
    float4 e;
    e.x = __builtin_amdgcn_exp2f((sc.x - m) * LOG2E_F);
    e.y = __builtin_amdgcn_exp2f((sc.y - m) * LOG2E_F);
    e.z = __builtin_amdgcn_exp2f((sc.z - m) * LOG2E_F);
    e.w = __builtin_amdgcn_exp2f((sc.w - m) * LOG2E_F);
    float sl = (e.x + e.y) + (e.z + e.w);
    #pragma unroll
    for (int mask = 32; mask >= 1; mask >>= 1) sl += __shfl_xor(sl, mask);
    float rs = __builtin_amdgcn_rcpf(sl);
    float4 o = make_float4(e.x * rs, e.y * rs, e.z * rs, e.w * rs);
    *(float4*)&attn[((size_t)(b * Q_ + q0 + qg)) * K_ + 4 * lane] = o;
  }
}

// ---------------------------------------------------------------------------
// Kernel 3: PV GEMM  out[b] = attn[b](256x256) @ values[b](256x512).
// proj-clone: 64x64 tiles, grid 256 (b=id&7, qt=(id>>3)&3, dvt=id>>5).
// attn rows are pre-normalized: no epilogue scaling.
// ---------------------------------------------------------------------------
__global__ __launch_bounds__(256) void pv_kernel(
    const float* __restrict__ attn, const float* __restrict__ values,
    float* __restrict__ out) {
  const int id  = blockIdx.x;
  const int b   = id & 7;
  const int qt  = (id >> 3) & 3;           // 64-q tile
  const int dvt = id >> 5;                 // 64-dv tile (0..7)
  const int tid = threadIdx.x;

  __shared__ float As[64][68];             // [k][q]  (attn^T tile)
  __shared__ float Bs[64][68];             // [k][dv] (values tile)

  const int lr = tid >> 4;
  const int lc = (tid & 15) << 2;
  const int r0 = (tid & 15) << 2;
  const int c0 = (tid >> 4) << 2;

  float acc[4][4] = {};

  for (int kk = 0; kk < K_; kk += 64) {
    #pragma unroll
    for (int i = 0; i < 4; i++) {
      const int row = lr + i * 16;
      float4 va = *(const float4*)&attn[((size_t)(b * Q_ + qt * 64 + row)) * K_ + kk + lc];
      As[lc + 0][row] = va.x; As[lc + 1][row] = va.y;
      As[lc + 2][row] = va.z; As[lc + 3][row] = va.w;
      float4 vb = *(const float4*)&values[((size_t)(b * K_ + kk + row)) * DV_ + dvt * 64 + lc];
      *(float4*)&Bs[row][lc] = vb;
    }
    __syncthreads();

    #pragma unroll 8
    for (int d = 0; d < 64; d++) {
      float4 av = *(const float4*)&As[d][r0];
      float4 bv = *(const float4*)&Bs[d][c0];
      acc[0][0] = fmaf(av.x, bv.x, acc[0][0]); acc[0][1] = fmaf(av.x, bv.y, acc[0][1]);
      acc[0][2] = fmaf(av.x, bv.z, acc[0][2]); acc[0][3] = fmaf(av.x, bv.w, acc[0][3]);
      acc[1][0] = fmaf(av.y, bv.x, acc[1][0]); acc[1][1] = fmaf(av.y, bv.y, acc[1][1]);
      acc[1][2] = fmaf(av.y, bv.z, acc[1][2]); acc[1][3] = fmaf(av.y, bv.w, acc[1][3]);
      acc[2][0] = fmaf(av.z, bv.x, acc[2][0]); acc[2][1] = fmaf(av.z, bv.y, acc[2][1]);
      acc[2][2] = fmaf(av.z, bv.z, acc[2][2]); acc[2][3] = fmaf(av.z, bv.w, acc[2][3]);
      acc[3][0] = fmaf(av.w, bv.x, acc[3][0]); acc[3][1] = fmaf(av.w, bv.y, acc[3][1]);
      acc[3][2] = fmaf(av.w, bv.z, acc[3][2]); acc[3][3] = fmaf(av.w, bv.w, acc[3][3]);
    }
    __syncthreads();
  }

  #pragma unroll
  for (int i = 0; i < 4; i++) {
    float4 o = make_float4(acc[i][0], acc[i][1], acc[i][2], acc[i][3]);
    *(float4*)&out[((size_t)(b * Q_ + qt * 64 + r0 + i)) * DV_ + dvt * 64 + c0] = o;
  }
}

extern "C" void kernel_launch(void* const* d_in, const int* in_sizes, int n_in,
                              void* d_out, int out_size, void* d_ws, size_t ws_size,
                              hipStream_t stream) {
  const float* queries = (const float*)d_in[0];  // [8,256,256]
  const float* keys    = (const float*)d_in[1];  // [8,256,256]
  const float* values  = (const float*)d_in[2];  // [8,256,512]
  const float* W_q     = (const float*)d_in[3];  // [256,256]
  const float* W_k     = (const float*)d_in[4];  // [256,256]
  const float* w_v     = (const float*)d_in[5];  // [256]
  float* out = (float*)d_out;

  float* Eq   = (float*)d_ws;                    // [8][256][256] = 2 MB
  float* EkT  = Eq  + (size_t)B_ * Q_ * H_;      // [8][256][256] = 2 MB
  float* attn = EkT + (size_t)B_ * H_ * K_;      // [8][256][256] = 2 MB

  dim3 pgrid(256), pblk(256);
  proj_kernel<<<pgrid, pblk, 0, stream>>>(queries, keys, W_q, W_k, Eq, EkT);

  dim3 sgrid(Q_ / QB * B_), sblk(512);           // 512 blocks
  score_kernel<<<sgrid, sblk, 0, stream>>>(Eq, EkT, w_v, attn);

  dim3 vgrid(256), vblk(256);
  pv_kernel<<<vgrid, vblk, 0, stream>>>(attn, values, out);
}

// Round 17
// 43.462 us; speedup vs baseline: 1.6583x; 1.0006x over previous
//
#include <hip/hip_runtime.h>
#include <hip/hip_bf16.h>

// Problem dims (fixed): B=8, Q=256, K=256, D=256, H=256, DV=512
#define B_  8
#define Q_  256
#define K_  256
#define D_  256
#define H_  256
#define DV_ 512
#define QB  2            // q-rows per score block (grid 1024 -> 32 waves/CU)

#define SCALE_2LOG2E 2.8853900817779268f   // 2*log2(e): exp(2x) = 2^(x*this)
#define LOG2E_F      1.4426950408889634f

// ---------------------------------------------------------------------------
// Kernel 1: projections + exponentiation (exp factorization):
//   Eq [B][Q][H]  = 2^((queries @ W_q) * 2log2e)
//   EkT[B][H][K]  = 2^((keys    @ W_k)^T * 2log2e)   (transposed)
// Flat 1D grid, b = id&7 (XCD-locality).
// ---------------------------------------------------------------------------
__global__ __launch_bounds__(256) void proj_kernel(
    const float* __restrict__ queries, const float* __restrict__ keys,
    const float* __restrict__ Wq, const float* __restrict__ Wk,
    float* __restrict__ Eq, float* __restrict__ EkT) {
  const int id = blockIdx.x;
  const int b  = id & 7;
  const bool kpath = (id >> 3) & 1;
  const int m0 = ((id >> 4) & 3) * 64;     // q-rows (qpath) or k-cols (kpath)
  const int h0 = ((id >> 6) & 3) * 64;
  const int tid = threadIdx.x;

  __shared__ float As[64][68];             // [d][row]
  __shared__ float Bs[64][68];             // [d][col]

  const int lr = tid >> 4;
  const int lc = (tid & 15) << 2;
  const int r0 = (tid & 15) << 2;
  const int c0 = (tid >> 4) << 2;

  float acc[4][4] = {};

  for (int kk = 0; kk < D_; kk += 64) {
    if (!kpath) {
      #pragma unroll
      for (int i = 0; i < 4; i++) {
        const int row = lr + i * 16;
        float4 va = *(const float4*)&queries[((size_t)(b * Q_ + m0 + row)) * D_ + kk + lc];
        As[lc + 0][row] = va.x; As[lc + 1][row] = va.y;
        As[lc + 2][row] = va.z; As[lc + 3][row] = va.w;
        float4 vb = *(const float4*)&Wq[((size_t)(kk + row)) * H_ + h0 + lc];
        *(float4*)&Bs[row][lc] = vb;
      }
    } else {
      #pragma unroll
      for (int i = 0; i < 4; i++) {
        const int row = lr + i * 16;
        float4 va = *(const float4*)&Wk[((size_t)(kk + row)) * H_ + h0 + lc];
        *(float4*)&As[row][lc] = va;
        float4 vb = *(const float4*)&keys[((size_t)(b * K_ + m0 + row)) * D_ + kk + lc];
        Bs[lc + 0][row] = vb.x; Bs[lc + 1][row] = vb.y;
        Bs[lc + 2][row] = vb.z; Bs[lc + 3][row] = vb.w;
      }
    }
    __syncthreads();

    #pragma unroll 8
    for (int d = 0; d < 64; d++) {
      float4 av = *(const float4*)&As[d][r0];
      float4 bv = *(const float4*)&Bs[d][c0];
      acc[0][0] = fmaf(av.x, bv.x, acc[0][0]); acc[0][1] = fmaf(av.x, bv.y, acc[0][1]);
      acc[0][2] = fmaf(av.x, bv.z, acc[0][2]); acc[0][3] = fmaf(av.x, bv.w, acc[0][3]);
      acc[1][0] = fmaf(av.y, bv.x, acc[1][0]); acc[1][1] = fmaf(av.y, bv.y, acc[1][1]);
      acc[1][2] = fmaf(av.y, bv.z, acc[1][2]); acc[1][3] = fmaf(av.y, bv.w, acc[1][3]);
      acc[2][0] = fmaf(av.z, bv.x, acc[2][0]); acc[2][1] = fmaf(av.z, bv.y, acc[2][1]);
      acc[2][2] = fmaf(av.z, bv.z, acc[2][2]); acc[2][3] = fmaf(av.z, bv.w, acc[2][3]);
      acc[3][0] = fmaf(av.w, bv.x, acc[3][0]); acc[3][1] = fmaf(av.w, bv.y, acc[3][1]);
      acc[3][2] = fmaf(av.w, bv.z, acc[3][2]); acc[3][3] = fmaf(av.w, bv.w, acc[3][3]);
    }
    __syncthreads();
  }

  float* dst = kpath ? EkT : Eq;
  const int ro = kpath ? h0 : m0, co = kpath ? m0 : h0;
  #pragma unroll
  for (int i = 0; i < 4; i++) {
    float4 v;
    v.x = __builtin_amdgcn_exp2f(acc[i][0] * SCALE_2LOG2E);
    v.y = __builtin_amdgcn_exp2f(acc[i][1] * SCALE_2LOG2E);
    v.z = __builtin_amdgcn_exp2f(acc[i][2] * SCALE_2LOG2E);
    v.w = __builtin_amdgcn_exp2f(acc[i][3] * SCALE_2LOG2E);
    *(float4*)&dst[((size_t)(b * 256 + ro + r0 + i)) * 256 + co + c0] = v;
  }
}

// ---------------------------------------------------------------------------
// Kernel 2: scores + softmax.  QB=2, 512 threads (8 waves), grid 1024 ->
// 4 blocks/CU = 32 waves/CU (the VGPR<=64 hardware cap).  r15/r16's grid 512
// left HALF the wave slots empty (16 waves/CU) — every "2 blocks/CU" design
// since r11 was grid-capped at 50% occupancy, matching the persistent ~3x
// issue-stall.  Per-wave state shrinks (s2v[2], 3 uniform s_loads per step)
// so VGPR ~50 stays under the 64/32-wave boundary.
// SCORE: wave wid owns h-chunk [32*wid,+32), lane owns k=4*lane..+3.
//        4-way h-combined sigmoids (1 rcp / 4 h); eq/wv via scalar loads.
// REDUCE: two-pass into 4 slots (8 KB); waves 0-1 softmax + normalized store.
// ---------------------------------------------------------------------------
__global__ __launch_bounds__(512) void score_kernel(
    const float* __restrict__ Eq, const float* __restrict__ EkT,
    const float* __restrict__ wv, float* __restrict__ attn) {
  const int t    = threadIdx.x;
  const int wid  = __builtin_amdgcn_readfirstlane(t >> 6);   // wave-uniform
  const int lane = t & 63;
  const int b    = blockIdx.x & 7;         // XCD-locality decode
  const int q0   = (blockIdx.x >> 3) * QB;

  __shared__ float rbuf[4 * QB * 256];     // 8 KB: two-pass partial slots

  float4 s2v[QB];
  #pragma unroll
  for (int qq = 0; qq < QB; qq++) s2v[qq] = make_float4(0.f, 0.f, 0.f, 0.f);

  const int hbase = wid * 32;
  const float* ekb = EkT + (size_t)b * H_ * K_ + (size_t)hbase * K_ + 4 * lane;
  const float* eq0 = Eq + ((size_t)(b * Q_ + q0)) * H_ + hbase;
  const float* wv0 = wv + hbase;

  for (int st = 0; st < 8; st++) {         // 4 h per step
    float4 ekc[4];
    #pragma unroll
    for (int j = 0; j < 4; j++)
      ekc[j] = *(const float4*)(ekb + (size_t)(st * 4 + j) * K_);
    const int h = st * 4;
    float4 wvv  = *(const float4*)&wv0[h];             // uniform -> s_load
    float4 eqv0 = *(const float4*)&eq0[0 * H_ + h];    // uniform -> s_load
    float4 eqv1 = *(const float4*)&eq0[1 * H_ + h];
    #define SCORE_QC(qq, eqv, C)                                              \
    {                                                                         \
      float d0 = fmaf(eqv.x, ekc[0].C, 1.0f);                                 \
      float d1 = fmaf(eqv.y, ekc[1].C, 1.0f);                                 \
      float d2 = fmaf(eqv.z, ekc[2].C, 1.0f);                                 \
      float d3 = fmaf(eqv.w, ekc[3].C, 1.0f);                                 \
      float p01 = d0 * d1, p23 = d2 * d3;                                     \
      float n01 = fmaf(wvv.x, d1, wvv.y * d0);                                \
      float n23 = fmaf(wvv.z, d3, wvv.w * d2);                                \
      float num = fmaf(n01, p23, n23 * p01);                                  \
      s2v[qq].C = fmaf(num, __builtin_amdgcn_rcpf(p01 * p23), s2v[qq].C);     \
    }
    SCORE_QC(0, eqv0, x) SCORE_QC(0, eqv0, y) SCORE_QC(0, eqv0, z) SCORE_QC(0, eqv0, w)
    SCORE_QC(1, eqv1, x) SCORE_QC(1, eqv1, y) SCORE_QC(1, eqv1, z) SCORE_QC(1, eqv1, w)
    #undef SCORE_QC
  }

  // ---- two-pass combine into 4 slots (contiguous runs, conflict-free) ----
  if (wid >= 4) {
    #pragma unroll
    for (int qq = 0; qq < QB; qq++)
      *(float4*)&rbuf[(wid - 4) * (QB * 256) + qq * 256 + 4 * lane] = s2v[qq];
  }
  __syncthreads();
  if (wid < 4) {
    #pragma unroll
    for (int qq = 0; qq < QB; qq++) {
      float* p = &rbuf[wid * (QB * 256) + qq * 256 + 4 * lane];
      float4 o = *(const float4*)p;
      o.x += s2v[qq].x; o.y += s2v[qq].y; o.z += s2v[qq].z; o.w += s2v[qq].w;
      *(float4*)p = o;
    }
  }
  __syncthreads();

  // ---- softmax + normalized store: wave qg owns row qg; lane holds 4 k ----
  if (wid < QB) {
    const int qg = wid;
    float4 sc = make_float4(0.f, 0.f, 0.f, 0.f);
    #pragma unroll
    for (int s = 0; s < 4; s++) {
      float4 p = *(const float4*)&rbuf[s * (QB * 256) + qg * 256 + 4 * lane];
      sc.x += p.x; sc.y += p.y; sc.z += p.z; sc.w += p.w;
    }
    // fold the -2 factor here (linear in the partial sums)
    sc.x *= -2.0f; sc.y *= -2.0f; sc.z *= -2.0f; sc.w *= -2.0f;
    float m = fmaxf(fmaxf(sc.x, sc.y), fmaxf(sc.z, sc.w));
    #pragma unroll
    for (int mask = 32; mask >= 1; mask >>= 1) m = fmaxf(m, __shfl_xor(m, mask));
    float4 e;
    e.x = __builtin_amdgcn_exp2f((sc.x - m) * LOG2E_F);
    e.y = __builtin_amdgcn_exp2f((sc.y - m) * LOG2E_F);
    e.z = __builtin_amdgcn_exp2f((sc.z - m) * LOG2E_F);
    e.w = __builtin_amdgcn_exp2f((sc.w - m) * LOG2E_F);
    float sl = (e.x + e.y) + (e.z + e.w);
    #pragma unroll
    for (int mask = 32; mask >= 1; mask >>= 1) sl += __shfl_xor(sl, mask);
    float rs = __builtin_amdgcn_rcpf(sl);
    float4 o = make_float4(e.x * rs, e.y * rs, e.z * rs, e.w * rs);
    *(float4*)&attn[((size_t)(b * Q_ + q0 + qg)) * K_ + 4 * lane] = o;
  }
}

// ---------------------------------------------------------------------------
// Kernel 3: PV GEMM  out[b] = attn[b](256x256) @ values[b](256x512).
// proj-clone: 64x64 tiles, grid 256 (b=id&7, qt=(id>>3)&3, dvt=id>>5).
// attn rows are pre-normalized: no epilogue scaling.
// ---------------------------------------------------------------------------
__global__ __launch_bounds__(256) void pv_kernel(
    const float* __restrict__ attn, const float* __restrict__ values,
    float* __restrict__ out) {
  const int id  = blockIdx.x;
  const int b   = id & 7;
  const int qt  = (id >> 3) & 3;           // 64-q tile
  const int dvt = id >> 5;                 // 64-dv tile (0..7)
  const int tid = threadIdx.x;

  __shared__ float As[64][68];             // [k][q]  (attn^T tile)
  __shared__ float Bs[64][68];             // [k][dv] (values tile)

  const int lr = tid >> 4;
  const int lc = (tid & 15) << 2;
  const int r0 = (tid & 15) << 2;
  const int c0 = (tid >> 4) << 2;

  float acc[4][4] = {};

  for (int kk = 0; kk < K_; kk += 64) {
    #pragma unroll
    for (int i = 0; i < 4; i++) {
      const int row = lr + i * 16;
      float4 va = *(const float4*)&attn[((size_t)(b * Q_ + qt * 64 + row)) * K_ + kk + lc];
      As[lc + 0][row] = va.x; As[lc + 1][row] = va.y;
      As[lc + 2][row] = va.z; As[lc + 3][row] = va.w;
      float4 vb = *(const float4*)&values[((size_t)(b * K_ + kk + row)) * DV_ + dvt * 64 + lc];
      *(float4*)&Bs[row][lc] = vb;
    }
    __syncthreads();

    #pragma unroll 8
    for (int d = 0; d < 64; d++) {
      float4 av = *(const float4*)&As[d][r0];
      float4 bv = *(const float4*)&Bs[d][c0];
      acc[0][0] = fmaf(av.x, bv.x, acc[0][0]); acc[0][1] = fmaf(av.x, bv.y, acc[0][1]);
      acc[0][2] = fmaf(av.x, bv.z, acc[0][2]); acc[0][3] = fmaf(av.x, bv.w, acc[0][3]);
      acc[1][0] = fmaf(av.y, bv.x, acc[1][0]); acc[1][1] = fmaf(av.y, bv.y, acc[1][1]);
      acc[1][2] = fmaf(av.y, bv.z, acc[1][2]); acc[1][3] = fmaf(av.y, bv.w, acc[1][3]);
      acc[2][0] = fmaf(av.z, bv.x, acc[2][0]); acc[2][1] = fmaf(av.z, bv.y, acc[2][1]);
      acc[2][2] = fmaf(av.z, bv.z, acc[2][2]); acc[2][3] = fmaf(av.z, bv.w, acc[2][3]);
      acc[3][0] = fmaf(av.w, bv.x, acc[3][0]); acc[3][1] = fmaf(av.w, bv.y, acc[3][1]);
      acc[3][2] = fmaf(av.w, bv.z, acc[3][2]); acc[3][3] = fmaf(av.w, bv.w, acc[3][3]);
    }
    __syncthreads();
  }

  #pragma unroll
  for (int i = 0; i < 4; i++) {
    float4 o = make_float4(acc[i][0], acc[i][1], acc[i][2], acc[i][3]);
    *(float4*)&out[((size_t)(b * Q_ + qt * 64 + r0 + i)) * DV_ + dvt * 64 + c0] = o;
  }
}

extern "C" void kernel_launch(void* const* d_in, const int* in_sizes, int n_in,
                              void* d_out, int out_size, void* d_ws, size_t ws_size,
                              hipStream_t stream) {
  const float* queries = (const float*)d_in[0];  // [8,256,256]
  const float* keys    = (const float*)d_in[1];  // [8,256,256]
  const float* values  = (const float*)d_in[2];  // [8,256,512]
  const float* W_q     = (const float*)d_in[3];  // [256,256]
  const float* W_k     = (const float*)d_in[4];  // [256,256]
  const float* w_v     = (const float*)d_in[5];  // [256]
  float* out = (float*)d_out;

  float* Eq   = (float*)d_ws;                    // [8][256][256] = 2 MB
  float* EkT  = Eq  + (size_t)B_ * Q_ * H_;      // [8][256][256] = 2 MB
  float* attn = EkT + (size_t)B_ * H_ * K_;      // [8][256][256] = 2 MB

  dim3 pgrid(256), pblk(256);
  proj_kernel<<<pgrid, pblk, 0, stream>>>(queries, keys, W_q, W_k, Eq, EkT);

  dim3 sgrid(Q_ / QB * B_), sblk(512);           // 1024 blocks, 4/CU
  score_kernel<<<sgrid, sblk, 0, stream>>>(Eq, EkT, w_v, attn);

  dim3 vgrid(256), vblk(256);
  pv_kernel<<<vgrid, vblk, 0, stream>>>(attn, values, out);
}

// Round 18
// 32.529 us; speedup vs baseline: 2.2156x; 1.3361x over previous
//
#include <hip/hip_runtime.h>
#include <hip/hip_bf16.h>

// Problem dims (fixed): B=8, Q=256, K=256, D=256, H=256, DV=512
#define B_  8
#define Q_  256
#define K_  256
#define D_  256
#define H_  256
#define DV_ 512
#define QB  2            // q-rows per score block

#define SCALE_2LOG2E 2.8853900817779268f   // 2*log2(e): exp(2x) = 2^(x*this)
#define LOG2E_F      1.4426950408889634f

typedef __attribute__((ext_vector_type(8))) short bf16x8;   // 8 bf16 = 4 VGPR
typedef __attribute__((ext_vector_type(4))) float f32x4;    // MFMA C/D

__device__ __forceinline__ uint f2bf(float f) {             // RNE f32->bf16
  uint u = __float_as_uint(f);
  return (u + 0x7FFFu + ((u >> 16) & 1u)) >> 16;
}
__device__ __forceinline__ uint pk(float lo, float hi) {
  return f2bf(lo) | (f2bf(hi) << 16);
}

// Stage a 64x64 f32 tile (row-major, leading dim ldg, base pre-offset) into
// LDS bf16 [64][72] (144B rows: 16B-aligned, ~2-way banks). Direct layout.
__device__ __forceinline__ void stage_direct(const float* g, int ldg,
                                             ushort (*lds)[72], int t) {
  const int sr = t >> 2, sc = (t & 3) * 16;
  const float* sp = g + (size_t)sr * ldg + sc;
  float4 v0 = ((const float4*)sp)[0];
  float4 v1 = ((const float4*)sp)[1];
  float4 v2 = ((const float4*)sp)[2];
  float4 v3 = ((const float4*)sp)[3];
  uint4 w0, w1;
  w0.x = pk(v0.x, v0.y); w0.y = pk(v0.z, v0.w);
  w0.z = pk(v1.x, v1.y); w0.w = pk(v1.z, v1.w);
  w1.x = pk(v2.x, v2.y); w1.y = pk(v2.z, v2.w);
  w1.z = pk(v3.x, v3.y); w1.w = pk(v3.z, v3.w);
  *(uint4*)&lds[sr][sc]     = w0;
  *(uint4*)&lds[sr][sc + 8] = w1;
}
// Stage TRANSPOSED: global [kdim][rdim] (rdim contiguous, leading dim ldg,
// base pre-offset to (k0,r0)) -> LDS [r][k] bf16 via 4x4 register transpose.
__device__ __forceinline__ void stage_trans(const float* g, int ldg,
                                            ushort (*lds)[72], int t) {
  const int kq = (t & 15) * 4, rq = (t >> 4) * 4;
  float4 a0 = *(const float4*)(g + (size_t)(kq + 0) * ldg + rq);
  float4 a1 = *(const float4*)(g + (size_t)(kq + 1) * ldg + rq);
  float4 a2 = *(const float4*)(g + (size_t)(kq + 2) * ldg + rq);
  float4 a3 = *(const float4*)(g + (size_t)(kq + 3) * ldg + rq);
  uint2 w;
  w.x = pk(a0.x, a1.x); w.y = pk(a2.x, a3.x); *(uint2*)&lds[rq + 0][kq] = w;
  w.x = pk(a0.y, a1.y); w.y = pk(a2.y, a3.y); *(uint2*)&lds[rq + 1][kq] = w;
  w.x = pk(a0.z, a1.z); w.y = pk(a2.z, a3.z); *(uint2*)&lds[rq + 2][kq] = w;
  w.x = pk(a0.w, a1.w); w.y = pk(a2.w, a3.w); *(uint2*)&lds[rq + 3][kq] = w;
}

// ---------------------------------------------------------------------------
// Kernel 1: projections + exp, via bf16 MFMA (16x16x32).
//   qpath: Eq[q][h]  = exp2( (queries @ Wq) * 2log2e )   A=queries  B=Wq^T
//   kpath: EkT[h][k] = exp2( (Wk^T @ keys^T) * 2log2e )  A=Wk^T     B=keys
// 64x64 out-tile/block, 4 waves: wave w owns rows [16w,16w+16) x all 64 cols.
// Fragments: A row = lane&15, B col = lane&15, k-window (lane>>4)*8 — with the
// SAME k convention on A and B the product is exact for ANY internal k-order
// (square CDNA A/B layouts are symmetric). C/D: row=(lane>>4)*4+r, col=lane&15
// [m89-verified].
// ---------------------------------------------------------------------------
__global__ __launch_bounds__(256) void proj_kernel(
    const float* __restrict__ queries, const float* __restrict__ keys,
    const float* __restrict__ Wq, const float* __restrict__ Wk,
    float* __restrict__ Eq, float* __restrict__ EkT) {
  const int id = blockIdx.x;
  const int b  = id & 7;                   // XCD-locality decode
  const bool kpath = (id >> 3) & 1;
  const int m0 = ((id >> 4) & 3) * 64;     // qpath: q rows; kpath: h rows
  const int n0 = ((id >> 6) & 3) * 64;     // qpath: h cols; kpath: k cols
  const int t  = threadIdx.x;

  __shared__ ushort Abuf[64][72];          // 9 KB
  __shared__ ushort Bbuf[64][72];          // 9 KB

  const int wv = t >> 6, l = t & 63, fr = l & 15, fg = l >> 4;

  f32x4 acc0 = {0.f, 0.f, 0.f, 0.f};
  f32x4 acc1 = acc0, acc2 = acc0, acc3 = acc0;

  for (int kk = 0; kk < D_; kk += 64) {
    if (!kpath) {
      stage_direct(queries + (size_t)(b * Q_ + m0) * D_ + kk, D_, Abuf, t);
      stage_trans (Wq + (size_t)kk * H_ + n0, H_, Bbuf, t);
    } else {
      stage_trans (Wk + (size_t)kk * H_ + m0, H_, Abuf, t);
      stage_direct(keys + (size_t)(b * K_ + n0) * D_ + kk, D_, Bbuf, t);
    }
    __syncthreads();
    #pragma unroll
    for (int ks = 0; ks < 2; ks++) {
      bf16x8 af = *(const bf16x8*)&Abuf[wv * 16 + fr][ks * 32 + fg * 8];
      bf16x8 b0 = *(const bf16x8*)&Bbuf[ 0 + fr][ks * 32 + fg * 8];
      bf16x8 b1 = *(const bf16x8*)&Bbuf[16 + fr][ks * 32 + fg * 8];
      bf16x8 b2 = *(const bf16x8*)&Bbuf[32 + fr][ks * 32 + fg * 8];
      bf16x8 b3 = *(const bf16x8*)&Bbuf[48 + fr][ks * 32 + fg * 8];
      acc0 = __builtin_amdgcn_mfma_f32_16x16x32_bf16(af, b0, acc0, 0, 0, 0);
      acc1 = __builtin_amdgcn_mfma_f32_16x16x32_bf16(af, b1, acc1, 0, 0, 0);
      acc2 = __builtin_amdgcn_mfma_f32_16x16x32_bf16(af, b2, acc2, 0, 0, 0);
      acc3 = __builtin_amdgcn_mfma_f32_16x16x32_bf16(af, b3, acc3, 0, 0, 0);
    }
    __syncthreads();
  }

  float* dst = kpath ? EkT : Eq;
  const int orow = m0 + wv * 16 + fg * 4;  // + r  (C/D row mapping, m89)
  #pragma unroll
  for (int r = 0; r < 4; r++) {
    size_t rowoff = (size_t)(b * 256 + orow + r) * 256 + n0 + fr;
    dst[rowoff +  0] = __builtin_amdgcn_exp2f(acc0[r] * SCALE_2LOG2E);
    dst[rowoff + 16] = __builtin_amdgcn_exp2f(acc1[r] * SCALE_2LOG2E);
    dst[rowoff + 32] = __builtin_amdgcn_exp2f(acc2[r] * SCALE_2LOG2E);
    dst[rowoff + 48] = __builtin_amdgcn_exp2f(acc3[r] * SCALE_2LOG2E);
  }
}

// ---------------------------------------------------------------------------
// Kernel 2: scores + softmax (r17, unchanged).  QB=2, 512 thr, grid 1024.
// ---------------------------------------------------------------------------
__global__ __launch_bounds__(512) void score_kernel(
    const float* __restrict__ Eq, const float* __restrict__ EkT,
    const float* __restrict__ wv, float* __restrict__ attn) {
  const int t    = threadIdx.x;
  const int wid  = __builtin_amdgcn_readfirstlane(t >> 6);   // wave-uniform
  const int lane = t & 63;
  const int b    = blockIdx.x & 7;         // XCD-locality decode
  const int q0   = (blockIdx.x >> 3) * QB;

  __shared__ float rbuf[4 * QB * 256];     // 8 KB: two-pass partial slots

  float4 s2v[QB];
  #pragma unroll
  for (int qq = 0; qq < QB; qq++) s2v[qq] = make_float4(0.f, 0.f, 0.f, 0.f);

  const int hbase = wid * 32;
  const float* ekb = EkT + (size_t)b * H_ * K_ + (size_t)hbase * K_ + 4 * lane;
  const float* eq0 = Eq + ((size_t)(b * Q_ + q0)) * H_ + hbase;
  const float* wv0 = wv + hbase;

  for (int st = 0; st < 8; st++) {         // 4 h per step
    float4 ekc[4];
    #pragma unroll
    for (int j = 0; j < 4; j++)
      ekc[j] = *(const float4*)(ekb + (size_t)(st * 4 + j) * K_);
    const int h = st * 4;
    float4 wvv  = *(const float4*)&wv0[h];             // uniform -> s_load
    float4 eqv0 = *(const float4*)&eq0[0 * H_ + h];    // uniform -> s_load
    float4 eqv1 = *(const float4*)&eq0[1 * H_ + h];
    #define SCORE_QC(qq, eqv, C)                                              \
    {                                                                         \
      float d0 = fmaf(eqv.x, ekc[0].C, 1.0f);                                 \
      float d1 = fmaf(eqv.y, ekc[1].C, 1.0f);                                 \
      float d2 = fmaf(eqv.z, ekc[2].C, 1.0f);                                 \
      float d3 = fmaf(eqv.w, ekc[3].C, 1.0f);                                 \
      float p01 = d0 * d1, p23 = d2 * d3;                                     \
      float n01 = fmaf(wvv.x, d1, wvv.y * d0);                                \
      float n23 = fmaf(wvv.z, d3, wvv.w * d2);                                \
      float num = fmaf(n01, p23, n23 * p01);                                  \
      s2v[qq].C = fmaf(num, __builtin_amdgcn_rcpf(p01 * p23), s2v[qq].C);     \
    }
    SCORE_QC(0, eqv0, x) SCORE_QC(0, eqv0, y) SCORE_QC(0, eqv0, z) SCORE_QC(0, eqv0, w)
    SCORE_QC(1, eqv1, x) SCORE_QC(1, eqv1, y) SCORE_QC(1, eqv1, z) SCORE_QC(1, eqv1, w)
    #undef SCORE_QC
  }

  // ---- two-pass combine into 4 slots (contiguous runs, conflict-free) ----
  if (wid >= 4) {
    #pragma unroll
    for (int qq = 0; qq < QB; qq++)
      *(float4*)&rbuf[(wid - 4) * (QB * 256) + qq * 256 + 4 * lane] = s2v[qq];
  }
  __syncthreads();
  if (wid < 4) {
    #pragma unroll
    for (int qq = 0; qq < QB; qq++) {
      float* p = &rbuf[wid * (QB * 256) + qq * 256 + 4 * lane];
      float4 o = *(const float4*)p;
      o.x += s2v[qq].x; o.y += s2v[qq].y; o.z += s2v[qq].z; o.w += s2v[qq].w;
      *(float4*)p = o;
    }
  }
  __syncthreads();

  // ---- softmax + normalized store: wave qg owns row qg; lane holds 4 k ----
  if (wid < QB) {
    const int qg = wid;
    float4 sc = make_float4(0.f, 0.f, 0.f, 0.f);
    #pragma unroll
    for (int s = 0; s < 4; s++) {
      float4 p = *(const float4*)&rbuf[s * (QB * 256) + qg * 256 + 4 * lane];
      sc.x += p.x; sc.y += p.y; sc.z += p.z; sc.w += p.w;
    }
    sc.x *= -2.0f; sc.y *= -2.0f; sc.z *= -2.0f; sc.w *= -2.0f;
    float m = fmaxf(fmaxf(sc.x, sc.y), fmaxf(sc.z, sc.w));
    #pragma unroll
    for (int mask = 32; mask >= 1; mask >>= 1) m = fmaxf(m, __shfl_xor(m, mask));
    float4 e;
    e.x = __builtin_amdgcn_exp2f((sc.x - m) * LOG2E_F);
    e.y = __builtin_amdgcn_exp2f((sc.y - m) * LOG2E_F);
    e.z = __builtin_amdgcn_exp2f((sc.z - m) * LOG2E_F);
    e.w = __builtin_amdgcn_exp2f((sc.w - m) * LOG2E_F);
    float sl = (e.x + e.y) + (e.z + e.w);
    #pragma unroll
    for (int mask = 32; mask >= 1; mask >>= 1) sl += __shfl_xor(sl, mask);
    float rs = __builtin_amdgcn_rcpf(sl);
    float4 o = make_float4(e.x * rs, e.y * rs, e.z * rs, e.w * rs);
    *(float4*)&attn[((size_t)(b * Q_ + q0 + qg)) * K_ + 4 * lane] = o;
  }
}

// ---------------------------------------------------------------------------
// Kernel 3: PV GEMM via bf16 MFMA: out[b] = attn[b] @ values[b].
// Same skeleton as proj: A = attn (direct), B = values^T (trans-stage).
// attn pre-normalized -> plain store epilogue.
// ---------------------------------------------------------------------------
__global__ __launch_bounds__(256) void pv_kernel(
    const float* __restrict__ attn, const float* __restrict__ values,
    float* __restrict__ out) {
  const int id  = blockIdx.x;
  const int b   = id & 7;
  const int m0  = ((id >> 3) & 3) * 64;    // q rows
  const int n0  = (id >> 5) * 64;          // dv cols (0..7)
  const int t   = threadIdx.x;

  __shared__ ushort Abuf[64][72];
  __shared__ ushort Bbuf[64][72];

  const int wv = t >> 6, l = t & 63, fr = l & 15, fg = l >> 4;

  f32x4 acc0 = {0.f, 0.f, 0.f, 0.f};
  f32x4 acc1 = acc0, acc2 = acc0, acc3 = acc0;

  for (int kk = 0; kk < K_; kk += 64) {
    stage_direct(attn + (size_t)(b * Q_ + m0) * K_ + kk, K_, Abuf, t);
    stage_trans (values + (size_t)(b * K_ + kk) * DV_ + n0, DV_, Bbuf, t);
    __syncthreads();
    #pragma unroll
    for (int ks = 0; ks < 2; ks++) {
      bf16x8 af = *(const bf16x8*)&Abuf[wv * 16 + fr][ks * 32 + fg * 8];
      bf16x8 b0 = *(const bf16x8*)&Bbuf[ 0 + fr][ks * 32 + fg * 8];
      bf16x8 b1 = *(const bf16x8*)&Bbuf[16 + fr][ks * 32 + fg * 8];
      bf16x8 b2 = *(const bf16x8*)&Bbuf[32 + fr][ks * 32 + fg * 8];
      bf16x8 b3 = *(const bf16x8*)&Bbuf[48 + fr][ks * 32 + fg * 8];
      acc0 = __builtin_amdgcn_mfma_f32_16x16x32_bf16(af, b0, acc0, 0, 0, 0);
      acc1 = __builtin_amdgcn_mfma_f32_16x16x32_bf16(af, b1, acc1, 0, 0, 0);
      acc2 = __builtin_amdgcn_mfma_f32_16x16x32_bf16(af, b2, acc2, 0, 0, 0);
      ac3:;
      acc3 = __builtin_amdgcn_mfma_f32_16x16x32_bf16(af, b3, acc3, 0, 0, 0);
    }
    __syncthreads();
  }

  const int orow = m0 + wv * 16 + fg * 4;
  #pragma unroll
  for (int r = 0; r < 4; r++) {
    size_t rowoff = (size_t)(b * Q_ + orow + r) * DV_ + n0 + fr;
    out[rowoff +  0] = acc0[r];
    out[rowoff + 16] = acc1[r];
    out[rowoff + 32] = acc2[r];
    out[rowoff + 48] = acc3[r];
  }
}

extern "C" void kernel_launch(void* const* d_in, const int* in_sizes, int n_in,
                              void* d_out, int out_size, void* d_ws, size_t ws_size,
                              hipStream_t stream) {
  const float* queries = (const float*)d_in[0];  // [8,256,256]
  const float* keys    = (const float*)d_in[1];  // [8,256,256]
  const float* values  = (const float*)d_in[2];  // [8,256,512]
  const float* W_q     = (const float*)d_in[3];  // [256,256]
  const float* W_k     = (const float*)d_in[4];  // [256,256]
  const float* w_v     = (const float*)d_in[5];  // [256]
  float* out = (float*)d_out;

  float* Eq   = (float*)d_ws;                    // [8][256][256] = 2 MB
  float* EkT  = Eq  + (size_t)B_ * Q_ * H_;      // [8][256][256] = 2 MB
  float* attn = EkT + (size_t)B_ * H_ * K_;      // [8][256][256] = 2 MB

  dim3 pgrid(256), pblk(256);
  proj_kernel<<<pgrid, pblk, 0, stream>>>(queries, keys, W_q, W_k, Eq, EkT);

  dim3 sgrid(Q_ / QB * B_), sblk(512);           // 1024 blocks
  score_kernel<<<sgrid, sblk, 0, stream>>>(Eq, EkT, w_v, attn);

  dim3 vgrid(256), vblk(256);
  pv_kernel<<<vgrid, vblk, 0, stream>>>(attn, values, out);
}